// Round 1
// baseline (272.592 us; speedup 1.0000x reference)
//
#include <hip/hip_runtime.h>

// Squared Euclidean distance: out[i][j] = ||a_i||^2 + ||b_j||^2 - 2 a_i.b_j
// a: [8192,128] fp32, b: [8192,128] fp32, out: [8192,8192] fp32.
// Strategy: exact fp32 row norms (kernel 1, into d_ws), bf16 MFMA GEMM for the
// cross term (kernel 2) with fused epilogue. Write-bound: 256 MiB out @6.3TB/s
// => ~41us floor.

typedef __attribute__((ext_vector_type(8))) short bf16x8;   // 8 bf16 = 4 VGPRs
typedef __attribute__((ext_vector_type(4))) float f32x4;    // MFMA acc

// fp32 -> bf16 round-to-nearest-even
__device__ __forceinline__ short f2bf(float f) {
    union { float f; unsigned u; } x; x.f = f;
    unsigned r = x.u + 0x7FFFu + ((x.u >> 16) & 1u);
    return (short)(r >> 16);
}

// ---------------- kernel 1: exact fp32 row norms ----------------
// one wave (64 lanes) per row of 128 floats: lane reads float2, shuffle-reduce.
__global__ void norms_kernel(const float* __restrict__ m1,
                             const float* __restrict__ m2,
                             float* __restrict__ n1,
                             float* __restrict__ n2,
                             int rows1, int rows2) {
    int gwave = (int)((blockIdx.x * blockDim.x + threadIdx.x) >> 6);
    int lane  = threadIdx.x & 63;
    const float* src;
    float* dst;
    int row;
    if (gwave < rows1) { src = m1; dst = n1; row = gwave; }
    else {
        row = gwave - rows1;
        if (row >= rows2) return;
        src = m2; dst = n2;
    }
    const float2* p = (const float2*)(src + (size_t)row * 128);
    float2 v = p[lane];
    float s = v.x * v.x + v.y * v.y;
#pragma unroll
    for (int off = 32; off; off >>= 1) s += __shfl_xor(s, off, 64);
    if (lane == 0) dst[row] = s;
}

// ---------------- kernel 2: bf16 MFMA cross-term + epilogue ----------------
#define BM 128
#define BN 128
#define BK 64

__global__ __launch_bounds__(256, 3)
void dist_kernel(const float* __restrict__ A, const float* __restrict__ B,
                 const float* __restrict__ n1, const float* __restrict__ n2,
                 float* __restrict__ out, int N2) {
    __shared__ short As[BM][BK];   // bf16 bits; row-major [m][k], 128B row stride
    __shared__ short Bs[BN][BK];   // [n][k]

    const int tid  = threadIdx.x;
    const int wave = tid >> 6;          // 0..3
    const int lane = tid & 63;
    const int q    = lane >> 4;         // quad 0..3
    const int l15  = lane & 15;

    const int ti = blockIdx.y * BM;     // rows of mat1
    const int tj = blockIdx.x * BN;     // rows of mat2 (= cols of out)

    const int wm = (wave >> 1) * 64;    // wave's 64x64 sub-tile
    const int wn = (wave & 1) * 64;

    f32x4 acc[4][4] = {};               // zero-init

    for (int kc = 0; kc < 128; kc += BK) {
        // ---- stage A tile: 128 rows x 64 k, fp32 -> bf16 ----
        // 1024 groups of 8 elements; 4 groups per thread.
#pragma unroll
        for (int g = 0; g < 4; ++g) {
            int idx = tid + g * 256;            // 0..1023
            int row = idx >> 3;
            int kg  = (idx & 7) * 8;
            const float4* pa = (const float4*)(A + (size_t)(ti + row) * 128 + kc + kg);
            float4 v0 = pa[0], v1 = pa[1];
            bf16x8 w;
            w[0] = f2bf(v0.x); w[1] = f2bf(v0.y); w[2] = f2bf(v0.z); w[3] = f2bf(v0.w);
            w[4] = f2bf(v1.x); w[5] = f2bf(v1.y); w[6] = f2bf(v1.z); w[7] = f2bf(v1.w);
            *(bf16x8*)&As[row][kg] = w;
        }
        // ---- stage B tile ----
#pragma unroll
        for (int g = 0; g < 4; ++g) {
            int idx = tid + g * 256;
            int row = idx >> 3;
            int kg  = (idx & 7) * 8;
            const float4* pb = (const float4*)(B + (size_t)(tj + row) * 128 + kc + kg);
            float4 v0 = pb[0], v1 = pb[1];
            bf16x8 w;
            w[0] = f2bf(v0.x); w[1] = f2bf(v0.y); w[2] = f2bf(v0.z); w[3] = f2bf(v0.w);
            w[4] = f2bf(v1.x); w[5] = f2bf(v1.y); w[6] = f2bf(v1.z); w[7] = f2bf(v1.w);
            *(bf16x8*)&Bs[row][kg] = w;
        }
        __syncthreads();

        // ---- MFMA over this K chunk ----
        // A frag: lane holds A[m = l15][k = q*8+j]; B frag: B[k = q*8+j][n = l15]
        // (both read 8 contiguous bf16 from a row => ds_read_b128)
#pragma unroll
        for (int kk = 0; kk < BK; kk += 32) {
            bf16x8 af[4], bfr[4];
#pragma unroll
            for (int mi = 0; mi < 4; ++mi)
                af[mi] = *(const bf16x8*)&As[wm + mi * 16 + l15][kk + q * 8];
#pragma unroll
            for (int ni = 0; ni < 4; ++ni)
                bfr[ni] = *(const bf16x8*)&Bs[wn + ni * 16 + l15][kk + q * 8];
#pragma unroll
            for (int mi = 0; mi < 4; ++mi)
#pragma unroll
                for (int ni = 0; ni < 4; ++ni)
                    acc[mi][ni] = __builtin_amdgcn_mfma_f32_16x16x32_bf16(
                        af[mi], bfr[ni], acc[mi][ni], 0, 0, 0);
        }
        __syncthreads();
    }

    // ---- epilogue: out = n1[r] + n2[c] - 2*cross ----
    // C/D layout: col = l15, row = q*4 + reg  (verified m89/m91)
#pragma unroll
    for (int mi = 0; mi < 4; ++mi) {
        int r0 = ti + wm + mi * 16 + q * 4;
        float a0 = n1[r0 + 0], a1 = n1[r0 + 1], a2 = n1[r0 + 2], a3 = n1[r0 + 3];
#pragma unroll
        for (int ni = 0; ni < 4; ++ni) {
            int c = tj + wn + ni * 16 + l15;
            float nb = n2[c];
            f32x4 v = acc[mi][ni];
            out[(size_t)(r0 + 0) * N2 + c] = a0 + nb - 2.0f * v[0];
            out[(size_t)(r0 + 1) * N2 + c] = a1 + nb - 2.0f * v[1];
            out[(size_t)(r0 + 2) * N2 + c] = a2 + nb - 2.0f * v[2];
            out[(size_t)(r0 + 3) * N2 + c] = a3 + nb - 2.0f * v[3];
        }
    }
}

extern "C" void kernel_launch(void* const* d_in, const int* in_sizes, int n_in,
                              void* d_out, int out_size, void* d_ws, size_t ws_size,
                              hipStream_t stream) {
    const float* m1 = (const float*)d_in[0];
    const float* m2 = (const float*)d_in[1];
    float* out = (float*)d_out;
    const int rows1 = in_sizes[0] / 128;   // 8192
    const int rows2 = in_sizes[1] / 128;   // 8192

    float* n1 = (float*)d_ws;
    float* n2 = n1 + rows1;

    int total_waves = rows1 + rows2;
    int nb = (total_waves * 64 + 255) / 256;
    norms_kernel<<<nb, 256, 0, stream>>>(m1, m2, n1, n2, rows1, rows2);

    dim3 grid(rows2 / BN, rows1 / BM);
    dist_kernel<<<grid, 256, 0, stream>>>(m1, m2, n1, n2, out, rows2);
}